// Round 1
// baseline (465.927 us; speedup 1.0000x reference)
//
#include <hip/hip_runtime.h>
#include <hip/hip_bf16.h>
#include <cstdint>
#include <cstddef>

typedef __attribute__((ext_vector_type(8))) __bf16 bf16x8;
typedef __attribute__((ext_vector_type(4))) float f32x4;
typedef __attribute__((ext_vector_type(4))) unsigned short u16x4;
typedef unsigned int u32;

#define NB 16
#define NC 512
#define NT 1024
#define NH 8
#define ND 64
#define NE 512

// async global->LDS, 16B per lane; lds ptr must be wave-uniform base
__device__ __forceinline__ void gld16(void* lds, const void* g) {
  __builtin_amdgcn_global_load_lds(
      (const __attribute__((address_space(1))) u32*)g,
      (__attribute__((address_space(3))) u32*)lds, 16, 0, 0);
}

__device__ __forceinline__ unsigned short f2bf(float f) {
  __bf16 h = (__bf16)f;
  return __builtin_bit_cast(unsigned short, h);
}

// ---------------- weight transpose + bf16 convert: Wt[c][r] = W[r][c] -------
__global__ __launch_bounds__(256) void wt_convert(
    const float* __restrict__ W, __bf16* __restrict__ Wt, int rows, int cols)
{
  const int idx = blockIdx.x * 256 + threadIdx.x;
  if (idx >= rows * cols) return;
  const int r = idx / cols, c = idx - r * cols;
  Wt[(size_t)c * rows + r] = (__bf16)W[idx];
}

// ---------------- LayerNorm over C after (B,C,T)->(B,T,C) transpose ---------
__global__ __launch_bounds__(256) void ln_kernel(
    const float* __restrict__ X, const float* __restrict__ gam,
    const float* __restrict__ bet, __bf16* __restrict__ xn)
{
  __shared__ float tile[16][513];   // padded: conflict-free transpose
  __shared__ float mu_s[16], rs_s[16];
  const int b  = blockIdx.x >> 6;
  const int t0 = (blockIdx.x & 63) << 4;
  const int tid = threadIdx.x;
  const int tl = tid & 15, c0 = tid >> 4;
  const float* Xb = X + (size_t)b * NC * NT + t0;
  for (int c = c0; c < NC; c += 16)
    tile[tl][c] = Xb[(size_t)c * NT + tl];
  __syncthreads();
  const int row = tid >> 4, sub = tid & 15;
  float s = 0.f, s2 = 0.f;
  for (int c = sub; c < NC; c += 16) { const float v = tile[row][c]; s += v; s2 += v * v; }
  s += __shfl_xor(s, 1);  s2 += __shfl_xor(s2, 1);
  s += __shfl_xor(s, 2);  s2 += __shfl_xor(s2, 2);
  s += __shfl_xor(s, 4);  s2 += __shfl_xor(s2, 4);
  s += __shfl_xor(s, 8);  s2 += __shfl_xor(s2, 8);
  const float mu   = s * (1.f / NC);
  const float var  = s2 * (1.f / NC) - mu * mu;
  const float rstd = rsqrtf(var + 1e-6f);
  if (sub == 0) { mu_s[row] = mu; rs_s[row] = rstd; }
  __syncthreads();
  __bf16* xo = xn + ((size_t)b * NT + t0) * NC;
  for (int i = tid; i < 16 * NC; i += 256) {
    const int r = i >> 9, c = i & (NC - 1);
    xo[(size_t)r * NC + c] = (__bf16)((tile[r][c] - mu_s[r]) * rs_s[r] * gam[c] + bet[c]);
  }
}

// ---------------- QKV GEMM: xn[16384][512] @ Wt[1536][512]^T ---------------
__global__ __launch_bounds__(256) void gemm_qkv(
    const __bf16* __restrict__ A, const __bf16* __restrict__ Wt,
    const float* __restrict__ bq, const float* __restrict__ bk, const float* __restrict__ bv,
    __bf16* __restrict__ qb, __bf16* __restrict__ kb, __bf16* __restrict__ vtb)
{
  __shared__ __align__(16) __bf16 lA[128 * 32];
  __shared__ __align__(16) __bf16 lB[128 * 32];
  const int tid = threadIdx.x;
  const int wv = tid >> 6, lane = tid & 63;
  const int mt = blockIdx.x & 127, nt = blockIdx.x >> 7;
  const int m0 = mt << 7, n0 = nt << 7;
  const int fr = lane & 15, kq = lane >> 4;
  const int wr = wv >> 1, wc = wv & 1;

  const __bf16* Ag0 = A + (size_t)(m0 + (tid >> 2)) * NC + (tid & 3) * 8;
  const __bf16* Ag1 = Ag0 + (size_t)64 * NC;
  const __bf16* Bg0 = Wt + (size_t)(n0 + (tid >> 2)) * NC + (tid & 3) * 8;
  const __bf16* Bg1 = Bg0 + (size_t)64 * NC;
  __bf16* lA0 = lA + wv * 512; __bf16* lA1 = lA + 2048 + wv * 512;
  __bf16* lB0 = lB + wv * 512; __bf16* lB1 = lB + 2048 + wv * 512;

  f32x4 acc[4][4] = {};
  for (int k0 = 0; k0 < NC; k0 += 32) {
    gld16(lA0, Ag0 + k0); gld16(lA1, Ag1 + k0);
    gld16(lB0, Bg0 + k0); gld16(lB1, Bg1 + k0);
    __syncthreads();
    bf16x8 af[4], bfr[4];
#pragma unroll
    for (int i = 0; i < 4; i++) {
      af[i]  = *(const bf16x8*)&lA[(wr * 64 + i * 16 + fr) * 32 + kq * 8];
      bfr[i] = *(const bf16x8*)&lB[(wc * 64 + i * 16 + fr) * 32 + kq * 8];
    }
#pragma unroll
    for (int i = 0; i < 4; i++)
#pragma unroll
      for (int j = 0; j < 4; j++)
        acc[i][j] = __builtin_amdgcn_mfma_f32_16x16x32_bf16(af[i], bfr[j], acc[i][j], 0, 0, 0);
    __syncthreads();
  }

  const int wsel = n0 >> 9;  // 0=q 1=k 2=v (uniform per block)
  const float* bias = (wsel == 0) ? bq : (wsel == 1) ? bk : bv;
#pragma unroll
  for (int i = 0; i < 4; i++) {
#pragma unroll
    for (int j = 0; j < 4; j++) {
      const int ng = (n0 & 511) + wc * 64 + j * 16 + fr;  // e index
      const int hh = ng >> 6, dd = ng & 63;
      const float bb = bias[ng];
#pragma unroll
      for (int r = 0; r < 4; r++) {
        const int mg = m0 + wr * 64 + i * 16 + kq * 4 + r;
        const int b = mg >> 10, t = mg & 1023;
        const __bf16 h16 = (__bf16)(acc[i][j][r] + bb);
        if (wsel == 0)      qb[(((size_t)b * NH + hh) * NT + t) * ND + dd] = h16;
        else if (wsel == 1) kb[(((size_t)b * NH + hh) * NT + t) * ND + dd] = h16;
        else                vtb[(((size_t)b * NH + hh) * ND + dd) * NT + t] = h16;  // V^T
      }
    }
  }
}

// ---------------- flash attention: S^T = mfma(K,Q), online softmax, PV -----
__global__ __launch_bounds__(256) void attn_kernel(
    const __bf16* __restrict__ qb, const __bf16* __restrict__ kb,
    const __bf16* __restrict__ vtb, __bf16* __restrict__ hb)
{
  __shared__ __align__(16) unsigned short P[4][16][72];  // per-wave P, padded pitch
  const int tid = threadIdx.x, wv = tid >> 6, lane = tid & 63;
  const int qt = blockIdx.x, hh = blockIdx.y, b = blockIdx.z;
  const int fr = lane & 15, g4 = lane >> 4;
  const int q0 = qt * 64 + wv * 16;
  const __bf16* Q  = qb  + ((size_t)b * NH + hh) * NT * ND;
  const __bf16* K  = kb  + ((size_t)b * NH + hh) * NT * ND;
  const __bf16* Vt = vtb + ((size_t)b * NH + hh) * ND * NT;

  const bf16x8 q_f0 = *(const bf16x8*)&Q[(q0 + fr) * ND + g4 * 8];
  const bf16x8 q_f1 = *(const bf16x8*)&Q[(q0 + fr) * ND + 32 + g4 * 8];

  float m_run = -1e30f, l_run = 0.f;
  f32x4 O[4] = {};

  for (int kt = 0; kt < NT; kt += 64) {
    f32x4 st[4];
#pragma unroll
    for (int rt = 0; rt < 4; rt++) {
      const bf16x8 ka0 = *(const bf16x8*)&K[(size_t)(kt + rt * 16 + fr) * ND + g4 * 8];
      const bf16x8 ka1 = *(const bf16x8*)&K[(size_t)(kt + rt * 16 + fr) * ND + 32 + g4 * 8];
      f32x4 z = {};
      z = __builtin_amdgcn_mfma_f32_16x16x32_bf16(ka0, q_f0, z, 0, 0, 0);
      z = __builtin_amdgcn_mfma_f32_16x16x32_bf16(ka1, q_f1, z, 0, 0, 0);
      st[rt] = z;
    }
    float tm = -1e30f;
#pragma unroll
    for (int rt = 0; rt < 4; rt++)
#pragma unroll
      for (int r = 0; r < 4; r++) {
        const float s = st[rt][r] * 0.125f;  // 1/sqrt(64)
        st[rt][r] = s;
        tm = fmaxf(tm, s);
      }
    tm = fmaxf(tm, __shfl_xor(tm, 16));
    tm = fmaxf(tm, __shfl_xor(tm, 32));
    const float m_new = fmaxf(m_run, tm);
    const float alpha = __expf(m_run - m_new);
    float rs = 0.f;
#pragma unroll
    for (int rt = 0; rt < 4; rt++) {
      u16x4 pk;
#pragma unroll
      for (int r = 0; r < 4; r++) {
        const float p = __expf(st[rt][r] - m_new);
        rs += p;
        pk[r] = f2bf(p);
      }
      *(u16x4*)&P[wv][fr][rt * 16 + g4 * 4] = pk;  // P[q][k_local]
    }
    rs += __shfl_xor(rs, 16);
    rs += __shfl_xor(rs, 32);
    l_run = l_run * alpha + rs;
    m_run = m_new;
    float af[4];
#pragma unroll
    for (int r = 0; r < 4; r++) af[r] = __shfl(alpha, g4 * 4 + r);  // alpha for O-row q
#pragma unroll
    for (int dt = 0; dt < 4; dt++)
#pragma unroll
      for (int r = 0; r < 4; r++) O[dt][r] *= af[r];
#pragma unroll
    for (int ks = 0; ks < 2; ks++) {
      const bf16x8 pa = *(const bf16x8*)&P[wv][fr][ks * 32 + g4 * 8];
#pragma unroll
      for (int dt = 0; dt < 4; dt++) {
        const bf16x8 vb = *(const bf16x8*)&Vt[(size_t)(dt * 16 + fr) * NT + kt + ks * 32 + g4 * 8];
        O[dt] = __builtin_amdgcn_mfma_f32_16x16x32_bf16(pa, vb, O[dt], 0, 0, 0);
      }
    }
  }
  float lf[4];
#pragma unroll
  for (int r = 0; r < 4; r++) lf[r] = 1.f / __shfl(l_run, g4 * 4 + r);
#pragma unroll
  for (int dt = 0; dt < 4; dt++)
#pragma unroll
    for (int r = 0; r < 4; r++) {
      const int t = q0 + g4 * 4 + r;
      hb[((size_t)b * NT + t) * NE + hh * ND + dt * 16 + fr] = (__bf16)(O[dt][r] * lf[r]);
    }
}

// ---------------- out proj + bias + residual + transpose store -------------
__global__ __launch_bounds__(256) void gemm_out(
    const __bf16* __restrict__ A, const __bf16* __restrict__ Wt,
    const float* __restrict__ bo, const float* __restrict__ X,
    float* __restrict__ out)
{
  __shared__ __align__(16) __bf16 lA[128 * 32];
  __shared__ __align__(16) __bf16 lB[128 * 32];
  __shared__ float tb[4][16][17];
  const int tid = threadIdx.x, wv = tid >> 6, lane = tid & 63;
  const int mt = blockIdx.x & 127, nt = blockIdx.x >> 7;
  const int m0 = mt << 7, n0 = nt << 7;
  const int fr = lane & 15, kq = lane >> 4;
  const int wr = wv >> 1, wc = wv & 1;

  const __bf16* Ag0 = A + (size_t)(m0 + (tid >> 2)) * NE + (tid & 3) * 8;
  const __bf16* Ag1 = Ag0 + (size_t)64 * NE;
  const __bf16* Bg0 = Wt + (size_t)(n0 + (tid >> 2)) * NE + (tid & 3) * 8;
  const __bf16* Bg1 = Bg0 + (size_t)64 * NE;
  __bf16* lA0 = lA + wv * 512; __bf16* lA1 = lA + 2048 + wv * 512;
  __bf16* lB0 = lB + wv * 512; __bf16* lB1 = lB + 2048 + wv * 512;

  f32x4 acc[4][4] = {};
  for (int k0 = 0; k0 < NE; k0 += 32) {
    gld16(lA0, Ag0 + k0); gld16(lA1, Ag1 + k0);
    gld16(lB0, Bg0 + k0); gld16(lB1, Bg1 + k0);
    __syncthreads();
    bf16x8 af[4], bfr[4];
#pragma unroll
    for (int i = 0; i < 4; i++) {
      af[i]  = *(const bf16x8*)&lA[(wr * 64 + i * 16 + fr) * 32 + kq * 8];
      bfr[i] = *(const bf16x8*)&lB[(wc * 64 + i * 16 + fr) * 32 + kq * 8];
    }
#pragma unroll
    for (int i = 0; i < 4; i++)
#pragma unroll
      for (int j = 0; j < 4; j++)
        acc[i][j] = __builtin_amdgcn_mfma_f32_16x16x32_bf16(af[i], bfr[j], acc[i][j], 0, 0, 0);
    __syncthreads();
  }

#pragma unroll 1
  for (int i = 0; i < 4; i++)
#pragma unroll 1
    for (int j = 0; j < 4; j++) {
#pragma unroll
      for (int r = 0; r < 4; r++) tb[wv][kq * 4 + r][fr] = acc[i][j][r];
      __syncthreads();
#pragma unroll
      for (int rr = 0; rr < 4; rr++) {
        const int cloc = kq * 4 + rr;
        const int mg = m0 + wr * 64 + i * 16 + fr;
        const int b = mg >> 10, t = mg & 1023;
        const int c = n0 + wc * 64 + j * 16 + cloc;
        out[((size_t)b * NC + c) * NT + t] =
            tb[wv][fr][cloc] + bo[c] + X[((size_t)b * NC + c) * NT + t];
      }
      __syncthreads();
    }
}

// ---------------------------------------------------------------------------
extern "C" void kernel_launch(void* const* d_in, const int* in_sizes, int n_in,
                              void* d_out, int out_size, void* d_ws, size_t ws_size,
                              hipStream_t stream) {
  const float* X   = (const float*)d_in[0];
  const float* lng = (const float*)d_in[1];
  const float* lnb = (const float*)d_in[2];
  const float* Wq  = (const float*)d_in[3];
  const float* bq  = (const float*)d_in[4];
  const float* Wk  = (const float*)d_in[5];
  const float* bk  = (const float*)d_in[6];
  const float* Wv  = (const float*)d_in[7];
  const float* bv  = (const float*)d_in[8];
  const float* Wo  = (const float*)d_in[9];
  const float* bo  = (const float*)d_in[10];
  float* out = (float*)d_out;

  // workspace layout (bf16 elements); total = 42,991,616 elem = 86 MB
  __bf16* wsb   = (__bf16*)d_ws;
  __bf16* Wtqkv = wsb;                 // [1536][512]
  __bf16* Wot   = wsb + 786432;        // [512][512]
  __bf16* xn    = wsb + 1048576;       // [16384][512]
  __bf16* qbuf  = wsb + 9437184;       // [B][H][T][D]
  __bf16* kbuf  = wsb + 17825792;      // [B][H][T][D]
  __bf16* vtbuf = wsb + 26214400;      // [B][H][D][T]
  __bf16* hbuf  = wsb + 34603008;      // [16384][512]

  const int cvt_blocks = (512 * 512 + 255) / 256;
  wt_convert<<<cvt_blocks, 256, 0, stream>>>(Wq, Wtqkv,          512, 512);
  wt_convert<<<cvt_blocks, 256, 0, stream>>>(Wk, Wtqkv + 262144, 512, 512);
  wt_convert<<<cvt_blocks, 256, 0, stream>>>(Wv, Wtqkv + 524288, 512, 512);
  wt_convert<<<cvt_blocks, 256, 0, stream>>>(Wo, Wot,            512, 512);
  ln_kernel<<<NB * (NT / 16), 256, 0, stream>>>(X, lng, lnb, xn);
  gemm_qkv<<<128 * 12, 256, 0, stream>>>(xn, Wtqkv, bq, bk, bv, qbuf, kbuf, vtbuf);
  attn_kernel<<<dim3(NT / 64, NH, NB), 256, 0, stream>>>(qbuf, kbuf, vtbuf, hbuf);
  gemm_out<<<128 * 4, 256, 0, stream>>>(hbuf, Wot, bo, X, out);
}